// Round 1
// baseline (1842.528 us; speedup 1.0000x reference)
//
#include <hip/hip_runtime.h>

// Problem constants (verified against in_sizes at launch)
#define D 64
#define IN_DIM 192   // 3*D
#define H 256
#define NB 64        // nodes per MLP block
#define BLK 256

// ---------------------------------------------------------------------------
// Kernel 1: build X = [N][192] in workspace.
// cols [0,64): in_agg (zeroed), [64,128): out_agg (zeroed), [128,192): node_feat
// ---------------------------------------------------------------------------
__global__ void init_x_kernel(const float* __restrict__ node_feat,
                              float* __restrict__ X, int N) {
    int i = blockIdx.x * blockDim.x + threadIdx.x;   // one float4 per thread
    int total = N * 48;                               // 48 float4 per row
    if (i >= total) return;
    int n = i / 48;
    int c4 = i - n * 48;
    float4 v;
    if (c4 < 32) {
        v = make_float4(0.f, 0.f, 0.f, 0.f);
    } else {
        v = *(const float4*)(node_feat + (size_t)n * D + (c4 - 32) * 4);
    }
    *(float4*)(X + (size_t)n * IN_DIM + c4 * 4) = v;
}

// ---------------------------------------------------------------------------
// Kernel 2: edge scatter. 16 threads per edge (one float4 each).
// in-agg lives at X[r][0:64], out-agg at X[s][64:128].
// ---------------------------------------------------------------------------
__global__ void scatter_kernel(const float* __restrict__ edge_feat,
                               const int* __restrict__ senders,
                               const int* __restrict__ receivers,
                               float* __restrict__ X, int n_edges) {
    int i = blockIdx.x * blockDim.x + threadIdx.x;
    int total = n_edges * 16;
    if (i >= total) return;
    int e = i >> 4;
    int j = i & 15;
    const float4 v = *(const float4*)(edge_feat + (size_t)e * D + j * 4);
    int r = receivers[e];
    int s = senders[e];
    float* pi = X + (size_t)r * IN_DIM + j * 4;        // in-agg slot
    float* po = X + (size_t)s * IN_DIM + D + j * 4;    // out-agg slot
    atomicAdd(pi + 0, v.x); atomicAdd(pi + 1, v.y);
    atomicAdd(pi + 2, v.z); atomicAdd(pi + 3, v.w);
    atomicAdd(po + 0, v.x); atomicAdd(po + 1, v.y);
    atomicAdd(po + 2, v.z); atomicAdd(po + 3, v.w);
}

// ---------------------------------------------------------------------------
// Kernel 3: fused MLP  out = relu(X@W1 + b1)@W2 + b2
// 64 nodes per block, 256 threads.
// Phase 1: Xs[64][196] (50176 B) + W1 chunk [16][256] (16384 B) -> acc[8][8]/thread
//          W2s[256][64] (65536 B) staged at offset 66560 during phase 1.
// Phase 2: Hs[64][260] (66560 B, aliases Xs+W1s) x W2s -> out.
// Total LDS: 132096 B (1 block/CU).
// ---------------------------------------------------------------------------
#define XS_STRIDE 196
#define HS_STRIDE 260
#define SMEM_BYTES 132096

__device__ __forceinline__ void fma_row(float a, const float4 w, float* acc4) {
    acc4[0] = fmaf(a, w.x, acc4[0]);
    acc4[1] = fmaf(a, w.y, acc4[1]);
    acc4[2] = fmaf(a, w.z, acc4[2]);
    acc4[3] = fmaf(a, w.w, acc4[3]);
}

__global__ __launch_bounds__(BLK, 1) void mlp_kernel(
    const float* __restrict__ X,
    const float* __restrict__ W1, const float* __restrict__ b1,
    const float* __restrict__ W2, const float* __restrict__ b2,
    float* __restrict__ out, int N) {
    __shared__ __align__(16) char smem_raw[SMEM_BYTES];
    float* Xs  = (float*)smem_raw;             // [64][196]
    float* W1s = (float*)(smem_raw + 50176);   // [16][256]
    float* Hs  = (float*)smem_raw;             // [64][260]  (phase 2, aliases)
    float* W2s = (float*)(smem_raw + 66560);   // [256][64]

    const int t = threadIdx.x;
    const int n0 = blockIdx.x * NB;

    // Stage W2 (disjoint LDS region; no barrier needed until phase 2)
    #pragma unroll
    for (int q = 0; q < 16; ++q) {
        int idx = t + q * BLK;                 // float4 index 0..4095
        *(float4*)(W2s + idx * 4) = *(const float4*)(W2 + idx * 4);
    }

    // Stage X tile [NB][192] -> Xs[NB][196]
    for (int idx = t; idx < NB * 48; idx += BLK) {
        int n = idx / 48;
        int c4 = idx - n * 48;
        int node = n0 + n;
        float4 v = make_float4(0.f, 0.f, 0.f, 0.f);
        if (node < N) v = *(const float4*)(X + (size_t)node * IN_DIM + c4 * 4);
        *(float4*)(Xs + n * XS_STRIDE + c4 * 4) = v;
    }

    // Phase 1: hcat = relu(X@W1 + b1). Thread t: nodes tn*8..+7, cols {4tc..+3, 128+4tc..+3}
    const int tc = t & 31;
    const int tn = t >> 5;

    float acc[8][8];
    {
        float4 bA = *(const float4*)(b1 + 4 * tc);
        float4 bB = *(const float4*)(b1 + 128 + 4 * tc);
        #pragma unroll
        for (int i = 0; i < 8; ++i) {
            acc[i][0] = bA.x; acc[i][1] = bA.y; acc[i][2] = bA.z; acc[i][3] = bA.w;
            acc[i][4] = bB.x; acc[i][5] = bB.y; acc[i][6] = bB.z; acc[i][7] = bB.w;
        }
    }

    for (int k0 = 0; k0 < IN_DIM; k0 += 16) {
        __syncthreads();   // protect W1s from previous chunk's readers
        #pragma unroll
        for (int q = 0; q < 4; ++q) {
            int idx = t + q * BLK;             // float4 idx 0..1023
            int kk = idx >> 6;                 // 64 float4 per row of 256
            int cc = (idx & 63) << 2;
            *(float4*)(W1s + kk * H + cc) = *(const float4*)(W1 + (size_t)(k0 + kk) * H + cc);
        }
        __syncthreads();
        #pragma unroll
        for (int k = 0; k < 16; k += 4) {
            float4 xv[8];
            #pragma unroll
            for (int i = 0; i < 8; ++i)
                xv[i] = *(const float4*)(Xs + (tn * 8 + i) * XS_STRIDE + k0 + k);
            float4 wA[4], wB[4];
            #pragma unroll
            for (int kk = 0; kk < 4; ++kk) {
                wA[kk] = *(const float4*)(W1s + (k + kk) * H + 4 * tc);
                wB[kk] = *(const float4*)(W1s + (k + kk) * H + 128 + 4 * tc);
            }
            #pragma unroll
            for (int i = 0; i < 8; ++i) {
                fma_row(xv[i].x, wA[0], &acc[i][0]); fma_row(xv[i].x, wB[0], &acc[i][4]);
                fma_row(xv[i].y, wA[1], &acc[i][0]); fma_row(xv[i].y, wB[1], &acc[i][4]);
                fma_row(xv[i].z, wA[2], &acc[i][0]); fma_row(xv[i].z, wB[2], &acc[i][4]);
                fma_row(xv[i].w, wA[3], &acc[i][0]); fma_row(xv[i].w, wB[3], &acc[i][4]);
            }
        }
    }

    __syncthreads();   // done reading Xs; safe to overwrite with Hs

    #pragma unroll
    for (int i = 0; i < 8; ++i) {
        float4 a, b;
        a.x = fmaxf(acc[i][0], 0.f); a.y = fmaxf(acc[i][1], 0.f);
        a.z = fmaxf(acc[i][2], 0.f); a.w = fmaxf(acc[i][3], 0.f);
        b.x = fmaxf(acc[i][4], 0.f); b.y = fmaxf(acc[i][5], 0.f);
        b.z = fmaxf(acc[i][6], 0.f); b.w = fmaxf(acc[i][7], 0.f);
        *(float4*)(Hs + (tn * 8 + i) * HS_STRIDE + 4 * tc) = a;
        *(float4*)(Hs + (tn * 8 + i) * HS_STRIDE + 128 + 4 * tc) = b;
    }
    __syncthreads();   // Hs + W2s ready

    // Phase 2: out = Hs @ W2 + b2. Thread t: nodes tn2*4..+3, cols 4*tc2..+3
    const int tc2 = t & 15;
    const int tn2 = t >> 4;
    float4 o[4];
    {
        float4 bb = *(const float4*)(b2 + 4 * tc2);
        o[0] = bb; o[1] = bb; o[2] = bb; o[3] = bb;
    }
    #pragma unroll 4
    for (int k = 0; k < H; k += 4) {
        float4 h[4], w[4];
        #pragma unroll
        for (int i = 0; i < 4; ++i)
            h[i] = *(const float4*)(Hs + (tn2 * 4 + i) * HS_STRIDE + k);
        #pragma unroll
        for (int kk = 0; kk < 4; ++kk)
            w[kk] = *(const float4*)(W2s + (k + kk) * D + 4 * tc2);
        #pragma unroll
        for (int i = 0; i < 4; ++i) {
            fma_row(h[i].x, w[0], (float*)&o[i]);
            fma_row(h[i].y, w[1], (float*)&o[i]);
            fma_row(h[i].z, w[2], (float*)&o[i]);
            fma_row(h[i].w, w[3], (float*)&o[i]);
        }
    }
    #pragma unroll
    for (int i = 0; i < 4; ++i) {
        int node = n0 + tn2 * 4 + i;
        if (node < N)
            *(float4*)(out + (size_t)node * D + 4 * tc2) = o[i];
    }
}

// ---------------------------------------------------------------------------
extern "C" void kernel_launch(void* const* d_in, const int* in_sizes, int n_in,
                              void* d_out, int out_size, void* d_ws, size_t ws_size,
                              hipStream_t stream) {
    const float* node_feat = (const float*)d_in[0];
    const float* edge_feat = (const float*)d_in[1];
    const int*   senders   = (const int*)d_in[2];
    const int*   receivers = (const int*)d_in[3];
    const float* W1        = (const float*)d_in[4];
    const float* b1        = (const float*)d_in[5];
    const float* W2        = (const float*)d_in[6];
    const float* b2        = (const float*)d_in[7];
    float* out = (float*)d_out;

    const int N       = in_sizes[0] / D;
    const int n_edges = in_sizes[2];

    float* X = (float*)d_ws;   // [N][192], 38.4 MB

    {
        int total = N * 48;
        init_x_kernel<<<(total + BLK - 1) / BLK, BLK, 0, stream>>>(node_feat, X, N);
    }
    {
        int total = n_edges * 16;
        scatter_kernel<<<(total + BLK - 1) / BLK, BLK, 0, stream>>>(
            edge_feat, senders, receivers, X, n_edges);
    }
    {
        int nblk = (N + NB - 1) / NB;
        mlp_kernel<<<nblk, BLK, 0, stream>>>(X, W1, b1, W2, b2, out, N);
    }
}

// Round 4
// 782.213 us; speedup vs baseline: 2.3555x; 2.3555x over previous
//
#include <hip/hip_runtime.h>

// Problem constants
#define D 64
#define IN_DIM 192   // 3*D
#define H 256
#define NB 64        // nodes per MLP block
#define BLK 256
#define SCAN_BLK 512

// ---------------------------------------------------------------------------
// Workspace layout (all 4B aligned):
//   X      : N*192 floats          (38.4 MB)
//   deg    : 2N ints  (in||out degrees)
//   cursor : 2N ints
//   off    : 2N ints  (exclusive scan of deg)
//   bsums  : 256 ints
//   elist  : 2E ints  (in-edge lists for all nodes, then out-edge lists)
// ---------------------------------------------------------------------------

// Zero deg + cursor (laid out adjacently: 4N ints)
__global__ void zero_kernel(int* __restrict__ p, int n) {
    int i = blockIdx.x * blockDim.x + threadIdx.x;
    for (; i < n; i += gridDim.x * blockDim.x) p[i] = 0;
}

// Degree histogram: deg[recv] (in), deg[N+send] (out)
__global__ void hist_kernel(const int* __restrict__ senders,
                            const int* __restrict__ receivers,
                            int* __restrict__ deg, int n_edges, int N) {
    int e = blockIdx.x * blockDim.x + threadIdx.x;
    if (e >= n_edges) return;
    atomicAdd(&deg[receivers[e]], 1);
    atomicAdd(&deg[N + senders[e]], 1);
}

// Hierarchical exclusive scan over n (=2N) ints: deg -> off
__global__ void scan_a_kernel(const int* __restrict__ deg, int* __restrict__ off,
                              int* __restrict__ bsums, int n) {
    __shared__ int s[SCAN_BLK];
    int t = threadIdx.x;
    int gid = blockIdx.x * SCAN_BLK + t;
    int v = (gid < n) ? deg[gid] : 0;
    s[t] = v;
    for (int ofs = 1; ofs < SCAN_BLK; ofs <<= 1) {
        __syncthreads();
        int x = (t >= ofs) ? s[t - ofs] : 0;
        __syncthreads();
        s[t] += x;
    }
    __syncthreads();
    if (gid < n) off[gid] = s[t] - v;          // exclusive
    if (t == SCAN_BLK - 1) bsums[blockIdx.x] = s[t];
}

__global__ void scan_b_kernel(int* __restrict__ bsums, int nb) {
    __shared__ int s[256];
    int t = threadIdx.x;
    int v = (t < nb) ? bsums[t] : 0;
    s[t] = v;
    for (int ofs = 1; ofs < 256; ofs <<= 1) {
        __syncthreads();
        int x = (t >= ofs) ? s[t - ofs] : 0;
        __syncthreads();
        s[t] += x;
    }
    __syncthreads();
    if (t < nb) bsums[t] = s[t] - v;           // exclusive
}

__global__ void scan_c_kernel(int* __restrict__ off, const int* __restrict__ bsums, int n) {
    int gid = blockIdx.x * SCAN_BLK + threadIdx.x;
    if (gid < n) off[gid] += bsums[blockIdx.x];
}

// Fill edge-ID lists via atomic cursors
__global__ void fill_kernel(const int* __restrict__ senders,
                            const int* __restrict__ receivers,
                            const int* __restrict__ off,
                            int* __restrict__ cursor,
                            int* __restrict__ elist, int n_edges, int N) {
    int e = blockIdx.x * blockDim.x + threadIdx.x;
    if (e >= n_edges) return;
    int r = receivers[e];
    int p = atomicAdd(&cursor[r], 1);
    elist[off[r] + p] = e;
    int sd = senders[e];
    int q = atomicAdd(&cursor[N + sd], 1);
    elist[off[N + sd] + q] = e;
}

// Gather: one wave per segment (seg<N: in-agg -> X[:,0:64]; else out-agg -> X[:,64:128]).
// In-wave also copies node_feat -> X[:,128:192].
__global__ void gather_kernel(const float* __restrict__ edge_feat,
                              const float* __restrict__ node_feat,
                              const int* __restrict__ off,
                              const int* __restrict__ elist,
                              float* __restrict__ X, int N, int totE2) {
    int lane = threadIdx.x & 63;
    int seg = blockIdx.x * 4 + (threadIdx.x >> 6);
    if (seg >= 2 * N) return;
    int beg = off[seg];
    int end = (seg + 1 < 2 * N) ? off[seg + 1] : totE2;
    float acc = 0.f;
    for (int i = beg; i < end; ++i) {
        int e = elist[i];
        acc += edge_feat[(size_t)e * D + lane];
    }
    if (seg < N) {
        float* row = X + (size_t)seg * IN_DIM;
        row[lane] = acc;
        row[128 + lane] = node_feat[(size_t)seg * D + lane];
    } else {
        X[(size_t)(seg - N) * IN_DIM + D + lane] = acc;
    }
}

// ---------------------------------------------------------------------------
// Fused MLP  out = relu(X@W1 + b1)@W2 + b2
// ---------------------------------------------------------------------------
#define XS_STRIDE 196
#define HS_STRIDE 260
#define SMEM_BYTES 132096

__device__ __forceinline__ void fma_row(float a, const float4 w, float* acc4) {
    acc4[0] = fmaf(a, w.x, acc4[0]);
    acc4[1] = fmaf(a, w.y, acc4[1]);
    acc4[2] = fmaf(a, w.z, acc4[2]);
    acc4[3] = fmaf(a, w.w, acc4[3]);
}

__global__ __launch_bounds__(BLK, 1) void mlp_kernel(
    const float* __restrict__ X,
    const float* __restrict__ W1, const float* __restrict__ b1,
    const float* __restrict__ W2, const float* __restrict__ b2,
    float* __restrict__ out, int N) {
    __shared__ __align__(16) char smem_raw[SMEM_BYTES];
    float* Xs  = (float*)smem_raw;             // [64][196]
    float* W1s = (float*)(smem_raw + 50176);   // [16][256]
    float* Hs  = (float*)smem_raw;             // [64][260]  (phase 2, aliases)
    float* W2s = (float*)(smem_raw + 66560);   // [256][64]

    const int t = threadIdx.x;
    const int n0 = blockIdx.x * NB;

    #pragma unroll
    for (int q = 0; q < 16; ++q) {
        int idx = t + q * BLK;
        *(float4*)(W2s + idx * 4) = *(const float4*)(W2 + idx * 4);
    }

    for (int idx = t; idx < NB * 48; idx += BLK) {
        int n = idx / 48;
        int c4 = idx - n * 48;
        int node = n0 + n;
        float4 v = make_float4(0.f, 0.f, 0.f, 0.f);
        if (node < N) v = *(const float4*)(X + (size_t)node * IN_DIM + c4 * 4);
        *(float4*)(Xs + n * XS_STRIDE + c4 * 4) = v;
    }

    const int tc = t & 31;
    const int tn = t >> 5;

    float acc[8][8];
    {
        float4 bA = *(const float4*)(b1 + 4 * tc);
        float4 bB = *(const float4*)(b1 + 128 + 4 * tc);
        #pragma unroll
        for (int i = 0; i < 8; ++i) {
            acc[i][0] = bA.x; acc[i][1] = bA.y; acc[i][2] = bA.z; acc[i][3] = bA.w;
            acc[i][4] = bB.x; acc[i][5] = bB.y; acc[i][6] = bB.z; acc[i][7] = bB.w;
        }
    }

    for (int k0 = 0; k0 < IN_DIM; k0 += 16) {
        __syncthreads();
        #pragma unroll
        for (int q = 0; q < 4; ++q) {
            int idx = t + q * BLK;
            int kk = idx >> 6;
            int cc = (idx & 63) << 2;
            *(float4*)(W1s + kk * H + cc) = *(const float4*)(W1 + (size_t)(k0 + kk) * H + cc);
        }
        __syncthreads();
        #pragma unroll
        for (int k = 0; k < 16; k += 4) {
            float4 xv[8];
            #pragma unroll
            for (int i = 0; i < 8; ++i)
                xv[i] = *(const float4*)(Xs + (tn * 8 + i) * XS_STRIDE + k0 + k);
            float4 wA[4], wB[4];
            #pragma unroll
            for (int kk = 0; kk < 4; ++kk) {
                wA[kk] = *(const float4*)(W1s + (k + kk) * H + 4 * tc);
                wB[kk] = *(const float4*)(W1s + (k + kk) * H + 128 + 4 * tc);
            }
            #pragma unroll
            for (int i = 0; i < 8; ++i) {
                fma_row(xv[i].x, wA[0], &acc[i][0]); fma_row(xv[i].x, wB[0], &acc[i][4]);
                fma_row(xv[i].y, wA[1], &acc[i][0]); fma_row(xv[i].y, wB[1], &acc[i][4]);
                fma_row(xv[i].z, wA[2], &acc[i][0]); fma_row(xv[i].z, wB[2], &acc[i][4]);
                fma_row(xv[i].w, wA[3], &acc[i][0]); fma_row(xv[i].w, wB[3], &acc[i][4]);
            }
        }
    }

    __syncthreads();

    #pragma unroll
    for (int i = 0; i < 8; ++i) {
        float4 a, b;
        a.x = fmaxf(acc[i][0], 0.f); a.y = fmaxf(acc[i][1], 0.f);
        a.z = fmaxf(acc[i][2], 0.f); a.w = fmaxf(acc[i][3], 0.f);
        b.x = fmaxf(acc[i][4], 0.f); b.y = fmaxf(acc[i][5], 0.f);
        b.z = fmaxf(acc[i][6], 0.f); b.w = fmaxf(acc[i][7], 0.f);
        *(float4*)(Hs + (tn * 8 + i) * HS_STRIDE + 4 * tc) = a;
        *(float4*)(Hs + (tn * 8 + i) * HS_STRIDE + 128 + 4 * tc) = b;
    }
    __syncthreads();

    const int tc2 = t & 15;
    const int tn2 = t >> 4;
    float4 o[4];
    {
        float4 bb = *(const float4*)(b2 + 4 * tc2);
        o[0] = bb; o[1] = bb; o[2] = bb; o[3] = bb;
    }
    #pragma unroll 4
    for (int k = 0; k < H; k += 4) {
        float4 h[4], w[4];
        #pragma unroll
        for (int i = 0; i < 4; ++i)
            h[i] = *(const float4*)(Hs + (tn2 * 4 + i) * HS_STRIDE + k);
        #pragma unroll
        for (int kk = 0; kk < 4; ++kk)
            w[kk] = *(const float4*)(W2s + (k + kk) * D + 4 * tc2);
        #pragma unroll
        for (int i = 0; i < 4; ++i) {
            fma_row(h[i].x, w[0], (float*)&o[i]);
            fma_row(h[i].y, w[1], (float*)&o[i]);
            fma_row(h[i].z, w[2], (float*)&o[i]);
            fma_row(h[i].w, w[3], (float*)&o[i]);
        }
    }
    #pragma unroll
    for (int i = 0; i < 4; ++i) {
        int node = n0 + tn2 * 4 + i;
        if (node < N)
            *(float4*)(out + (size_t)node * D + 4 * tc2) = o[i];
    }
}

// ---------------------------------------------------------------------------
extern "C" void kernel_launch(void* const* d_in, const int* in_sizes, int n_in,
                              void* d_out, int out_size, void* d_ws, size_t ws_size,
                              hipStream_t stream) {
    const float* node_feat = (const float*)d_in[0];
    const float* edge_feat = (const float*)d_in[1];
    const int*   senders   = (const int*)d_in[2];
    const int*   receivers = (const int*)d_in[3];
    const float* W1        = (const float*)d_in[4];
    const float* b1        = (const float*)d_in[5];
    const float* W2        = (const float*)d_in[6];
    const float* b2        = (const float*)d_in[7];
    float* out = (float*)d_out;

    const int N       = in_sizes[0] / D;
    const int n_edges = in_sizes[2];
    const int totE2   = 2 * n_edges;
    const int n2      = 2 * N;

    float* X    = (float*)d_ws;                       // N*192 floats
    int* deg    = (int*)(X + (size_t)N * IN_DIM);     // 2N
    int* cursor = deg + n2;                           // 2N
    int* off    = cursor + n2;                        // 2N
    int* bsums  = off + n2;                           // 256
    int* elist  = bsums + 256;                        // 2E

    // 1. zero deg + cursor (adjacent, 4N ints)
    zero_kernel<<<196, BLK, 0, stream>>>(deg, 2 * n2);
    // 2. degree histogram
    hist_kernel<<<(n_edges + BLK - 1) / BLK, BLK, 0, stream>>>(
        senders, receivers, deg, n_edges, N);
    // 3. exclusive scan deg -> off
    int nb = (n2 + SCAN_BLK - 1) / SCAN_BLK;          // 196 for N=50000 (<=256 req.)
    scan_a_kernel<<<nb, SCAN_BLK, 0, stream>>>(deg, off, bsums, n2);
    scan_b_kernel<<<1, 256, 0, stream>>>(bsums, nb);
    scan_c_kernel<<<nb, SCAN_BLK, 0, stream>>>(off, bsums, n2);
    // 4. fill edge lists
    fill_kernel<<<(n_edges + BLK - 1) / BLK, BLK, 0, stream>>>(
        senders, receivers, off, cursor, elist, n_edges, N);
    // 5. gather into X (also copies node_feat)
    gather_kernel<<<(n2 + 3) / 4, BLK, 0, stream>>>(
        edge_feat, node_feat, off, elist, X, N, totE2);
    // 6. MLP
    mlp_kernel<<<(N + NB - 1) / NB, BLK, 0, stream>>>(X, W1, b1, W2, b2, out, N);
}

// Round 6
// 667.241 us; speedup vs baseline: 2.7614x; 1.1723x over previous
//
#include <hip/hip_runtime.h>

// Problem constants
#define D 64
#define IN_DIM 192   // 3*D
#define H 256
#define NB 64        // nodes per MLP block
#define BLK 256
#define MBLK 512
#define SCAN_BLK 512

// ---------------------------------------------------------------------------
// Workspace layout (all 4B aligned):
//   X      : N*192 floats          (38.4 MB)
//   deg    : 2N ints  (in||out degrees)
//   cursor : 2N ints
//   off    : 2N ints  (exclusive scan of deg)
//   bsums  : 256 ints
//   elist  : 2E ints  (in-edge lists for all nodes, then out-edge lists)
// ---------------------------------------------------------------------------

__global__ void zero_kernel(int* __restrict__ p, int n) {
    int i = blockIdx.x * blockDim.x + threadIdx.x;
    for (; i < n; i += gridDim.x * blockDim.x) p[i] = 0;
}

__global__ void hist_kernel(const int* __restrict__ senders,
                            const int* __restrict__ receivers,
                            int* __restrict__ deg, int n_edges, int N) {
    int e = blockIdx.x * blockDim.x + threadIdx.x;
    if (e >= n_edges) return;
    atomicAdd(&deg[receivers[e]], 1);
    atomicAdd(&deg[N + senders[e]], 1);
}

__global__ void scan_a_kernel(const int* __restrict__ deg, int* __restrict__ off,
                              int* __restrict__ bsums, int n) {
    __shared__ int s[SCAN_BLK];
    int t = threadIdx.x;
    int gid = blockIdx.x * SCAN_BLK + t;
    int v = (gid < n) ? deg[gid] : 0;
    s[t] = v;
    for (int ofs = 1; ofs < SCAN_BLK; ofs <<= 1) {
        __syncthreads();
        int x = (t >= ofs) ? s[t - ofs] : 0;
        __syncthreads();
        s[t] += x;
    }
    __syncthreads();
    if (gid < n) off[gid] = s[t] - v;          // exclusive
    if (t == SCAN_BLK - 1) bsums[blockIdx.x] = s[t];
}

__global__ void scan_b_kernel(int* __restrict__ bsums, int nb) {
    __shared__ int s[256];
    int t = threadIdx.x;
    int v = (t < nb) ? bsums[t] : 0;
    s[t] = v;
    for (int ofs = 1; ofs < 256; ofs <<= 1) {
        __syncthreads();
        int x = (t >= ofs) ? s[t - ofs] : 0;
        __syncthreads();
        s[t] += x;
    }
    __syncthreads();
    if (t < nb) bsums[t] = s[t] - v;           // exclusive
}

__global__ void scan_c_kernel(int* __restrict__ off, const int* __restrict__ bsums, int n) {
    int gid = blockIdx.x * SCAN_BLK + threadIdx.x;
    if (gid < n) off[gid] += bsums[blockIdx.x];
}

__global__ void fill_kernel(const int* __restrict__ senders,
                            const int* __restrict__ receivers,
                            const int* __restrict__ off,
                            int* __restrict__ cursor,
                            int* __restrict__ elist, int n_edges, int N) {
    int e = blockIdx.x * blockDim.x + threadIdx.x;
    if (e >= n_edges) return;
    int r = receivers[e];
    int p = atomicAdd(&cursor[r], 1);
    elist[off[r] + p] = e;
    int sd = senders[e];
    int q = atomicAdd(&cursor[N + sd], 1);
    elist[off[N + sd] + q] = e;
}

// ---------------------------------------------------------------------------
// Gather: one wave per segment. Lane layout: sub = lane>>4 (edge slot 0..3),
// c4 = lane&15 (float4 column). 4 edges processed in parallel, unrolled x2
// => 8 independent edge loads in flight per wave. Cross-slot reduce via
// shfl_xor(16)+shfl_xor(32); lanes 0..15 write the 64-col float4 result.
// ---------------------------------------------------------------------------
__global__ void gather_kernel(const float* __restrict__ edge_feat,
                              const float* __restrict__ node_feat,
                              const int* __restrict__ off,
                              const int* __restrict__ elist,
                              float* __restrict__ X, int N, int totE2) {
    int lane = threadIdx.x & 63;
    int seg = blockIdx.x * 4 + (threadIdx.x >> 6);
    if (seg >= 2 * N) return;
    int beg = off[seg];
    int end = (seg + 1 < 2 * N) ? off[seg + 1] : totE2;
    const int sub = lane >> 4;
    const int c4  = lane & 15;

    float4 a0 = make_float4(0.f, 0.f, 0.f, 0.f);
    float4 a1 = make_float4(0.f, 0.f, 0.f, 0.f);
    int i = beg + sub;
    for (; i + 4 < end; i += 8) {
        int e0 = elist[i];
        int e1 = elist[i + 4];
        const float4 v0 = *(const float4*)(edge_feat + (size_t)e0 * D + c4 * 4);
        const float4 v1 = *(const float4*)(edge_feat + (size_t)e1 * D + c4 * 4);
        a0.x += v0.x; a0.y += v0.y; a0.z += v0.z; a0.w += v0.w;
        a1.x += v1.x; a1.y += v1.y; a1.z += v1.z; a1.w += v1.w;
    }
    if (i < end) {
        int e = elist[i];
        const float4 v = *(const float4*)(edge_feat + (size_t)e * D + c4 * 4);
        a0.x += v.x; a0.y += v.y; a0.z += v.z; a0.w += v.w;
    }
    float4 a;
    a.x = a0.x + a1.x; a.y = a0.y + a1.y; a.z = a0.z + a1.z; a.w = a0.w + a1.w;
    a.x += __shfl_xor(a.x, 16); a.y += __shfl_xor(a.y, 16);
    a.z += __shfl_xor(a.z, 16); a.w += __shfl_xor(a.w, 16);
    a.x += __shfl_xor(a.x, 32); a.y += __shfl_xor(a.y, 32);
    a.z += __shfl_xor(a.z, 32); a.w += __shfl_xor(a.w, 32);

    if (seg < N) {
        float* row = X + (size_t)seg * IN_DIM;
        if (lane < 16) *(float4*)(row + 4 * c4) = a;
        row[128 + lane] = node_feat[(size_t)seg * D + lane];
    } else {
        if (lane < 16)
            *(float4*)(X + (size_t)(seg - N) * IN_DIM + D + 4 * c4) = a;
    }
}

// ---------------------------------------------------------------------------
// Fused MLP  out = relu(X@W1 + b1)@W2 + b2
// 64 nodes per block, 512 threads (8 waves => 2 waves/SIMD at 1 block/CU).
// LDS: Xs[64][196] (50176B) + W1s[16][256] (16384B), Hs[64][260] aliases,
//      W2s[256][64] at 66560. Total 132096B.
// ---------------------------------------------------------------------------
#define XS_STRIDE 196
#define HS_STRIDE 260
#define SMEM_BYTES 132096

__device__ __forceinline__ void fma_row(float a, const float4 w, float* acc4) {
    acc4[0] = fmaf(a, w.x, acc4[0]);
    acc4[1] = fmaf(a, w.y, acc4[1]);
    acc4[2] = fmaf(a, w.z, acc4[2]);
    acc4[3] = fmaf(a, w.w, acc4[3]);
}

__global__ __launch_bounds__(MBLK, 2) void mlp_kernel(
    const float* __restrict__ X,
    const float* __restrict__ W1, const float* __restrict__ b1,
    const float* __restrict__ W2, const float* __restrict__ b2,
    float* __restrict__ out, int N) {
    __shared__ __align__(16) char smem_raw[SMEM_BYTES];
    float* Xs  = (float*)smem_raw;             // [64][196]
    float* W1s = (float*)(smem_raw + 50176);   // [16][256]
    float* Hs  = (float*)smem_raw;             // [64][260]  (phase 2, aliases)
    float* W2s = (float*)(smem_raw + 66560);   // [256][64]

    const int t = threadIdx.x;
    const int n0 = blockIdx.x * NB;

    // Stage W2 (disjoint region; needed only after the phase-2 barrier)
    #pragma unroll
    for (int q = 0; q < 8; ++q) {
        int idx = t + q * MBLK;                // float4 index 0..4095
        *(float4*)(W2s + idx * 4) = *(const float4*)(W2 + idx * 4);
    }

    // Stage X tile [NB][192] -> Xs[NB][196]
    for (int idx = t; idx < NB * 48; idx += MBLK) {
        int n = idx / 48;
        int c4 = idx - n * 48;
        int node = n0 + n;
        float4 v = make_float4(0.f, 0.f, 0.f, 0.f);
        if (node < N) v = *(const float4*)(X + (size_t)node * IN_DIM + c4 * 4);
        *(float4*)(Xs + n * XS_STRIDE + c4 * 4) = v;
    }

    // Phase 1: thread t -> nodes tn*4..+3, cols {4tc..+3, 128+4tc..+3}
    const int tc = t & 31;
    const int tn = t >> 5;                     // 0..15

    float acc[4][8];
    {
        float4 bA = *(const float4*)(b1 + 4 * tc);
        float4 bB = *(const float4*)(b1 + 128 + 4 * tc);
        #pragma unroll
        for (int i = 0; i < 4; ++i) {
            acc[i][0] = bA.x; acc[i][1] = bA.y; acc[i][2] = bA.z; acc[i][3] = bA.w;
            acc[i][4] = bB.x; acc[i][5] = bB.y; acc[i][6] = bB.z; acc[i][7] = bB.w;
        }
    }

    for (int k0 = 0; k0 < IN_DIM; k0 += 16) {
        __syncthreads();   // protect W1s from previous chunk's readers
        #pragma unroll
        for (int q = 0; q < 2; ++q) {
            int idx = t + q * MBLK;            // float4 idx 0..1023
            int kk = idx >> 6;
            int cc = (idx & 63) << 2;
            *(float4*)(W1s + kk * H + cc) = *(const float4*)(W1 + (size_t)(k0 + kk) * H + cc);
        }
        __syncthreads();
        #pragma unroll
        for (int k = 0; k < 16; k += 4) {
            float4 xv[4];
            #pragma unroll
            for (int i = 0; i < 4; ++i)
                xv[i] = *(const float4*)(Xs + (tn * 4 + i) * XS_STRIDE + k0 + k);
            float4 wA[4], wB[4];
            #pragma unroll
            for (int kk = 0; kk < 4; ++kk) {
                wA[kk] = *(const float4*)(W1s + (k + kk) * H + 4 * tc);
                wB[kk] = *(const float4*)(W1s + (k + kk) * H + 128 + 4 * tc);
            }
            #pragma unroll
            for (int i = 0; i < 4; ++i) {
                fma_row(xv[i].x, wA[0], &acc[i][0]); fma_row(xv[i].x, wB[0], &acc[i][4]);
                fma_row(xv[i].y, wA[1], &acc[i][0]); fma_row(xv[i].y, wB[1], &acc[i][4]);
                fma_row(xv[i].z, wA[2], &acc[i][0]); fma_row(xv[i].z, wB[2], &acc[i][4]);
                fma_row(xv[i].w, wA[3], &acc[i][0]); fma_row(xv[i].w, wB[3], &acc[i][4]);
            }
        }
    }

    __syncthreads();   // done reading Xs; safe to overwrite with Hs

    #pragma unroll
    for (int i = 0; i < 4; ++i) {
        float4 a, b;
        a.x = fmaxf(acc[i][0], 0.f); a.y = fmaxf(acc[i][1], 0.f);
        a.z = fmaxf(acc[i][2], 0.f); a.w = fmaxf(acc[i][3], 0.f);
        b.x = fmaxf(acc[i][4], 0.f); b.y = fmaxf(acc[i][5], 0.f);
        b.z = fmaxf(acc[i][6], 0.f); b.w = fmaxf(acc[i][7], 0.f);
        *(float4*)(Hs + (tn * 4 + i) * HS_STRIDE + 4 * tc) = a;
        *(float4*)(Hs + (tn * 4 + i) * HS_STRIDE + 128 + 4 * tc) = b;
    }
    __syncthreads();   // Hs + W2s ready

    // Phase 2: thread t -> nodes tn2*2..+1, cols 4*tc2..+3
    const int tc2 = t & 15;
    const int tn2 = t >> 4;                    // 0..31
    float4 o[2];
    {
        float4 bb = *(const float4*)(b2 + 4 * tc2);
        o[0] = bb; o[1] = bb;
    }
    #pragma unroll 4
    for (int k = 0; k < H; k += 4) {
        float4 h[2], w[4];
        #pragma unroll
        for (int i = 0; i < 2; ++i)
            h[i] = *(const float4*)(Hs + (tn2 * 2 + i) * HS_STRIDE + k);
        #pragma unroll
        for (int kk = 0; kk < 4; ++kk)
            w[kk] = *(const float4*)(W2s + (k + kk) * D + 4 * tc2);
        #pragma unroll
        for (int i = 0; i < 2; ++i) {
            fma_row(h[i].x, w[0], (float*)&o[i]);
            fma_row(h[i].y, w[1], (float*)&o[i]);
            fma_row(h[i].z, w[2], (float*)&o[i]);
            fma_row(h[i].w, w[3], (float*)&o[i]);
        }
    }
    #pragma unroll
    for (int i = 0; i < 2; ++i) {
        int node = n0 + tn2 * 2 + i;
        if (node < N)
            *(float4*)(out + (size_t)node * D + 4 * tc2) = o[i];
    }
}

// ---------------------------------------------------------------------------
extern "C" void kernel_launch(void* const* d_in, const int* in_sizes, int n_in,
                              void* d_out, int out_size, void* d_ws, size_t ws_size,
                              hipStream_t stream) {
    const float* node_feat = (const float*)d_in[0];
    const float* edge_feat = (const float*)d_in[1];
    const int*   senders   = (const int*)d_in[2];
    const int*   receivers = (const int*)d_in[3];
    const float* W1        = (const float*)d_in[4];
    const float* b1        = (const float*)d_in[5];
    const float* W2        = (const float*)d_in[6];
    const float* b2        = (const float*)d_in[7];
    float* out = (float*)d_out;

    const int N       = in_sizes[0] / D;
    const int n_edges = in_sizes[2];
    const int totE2   = 2 * n_edges;
    const int n2      = 2 * N;

    float* X    = (float*)d_ws;                       // N*192 floats
    int* deg    = (int*)(X + (size_t)N * IN_DIM);     // 2N
    int* cursor = deg + n2;                           // 2N
    int* off    = cursor + n2;                        // 2N
    int* bsums  = off + n2;                           // 256
    int* elist  = bsums + 256;                        // 2E

    // 1. zero deg + cursor (adjacent, 4N ints)
    zero_kernel<<<196, BLK, 0, stream>>>(deg, 2 * n2);
    // 2. degree histogram
    hist_kernel<<<(n_edges + BLK - 1) / BLK, BLK, 0, stream>>>(
        senders, receivers, deg, n_edges, N);
    // 3. exclusive scan deg -> off
    int nb = (n2 + SCAN_BLK - 1) / SCAN_BLK;          // 196 for N=50000 (<=256 req.)
    scan_a_kernel<<<nb, SCAN_BLK, 0, stream>>>(deg, off, bsums, n2);
    scan_b_kernel<<<1, 256, 0, stream>>>(bsums, nb);
    scan_c_kernel<<<nb, SCAN_BLK, 0, stream>>>(off, bsums, n2);
    // 4. fill edge lists
    fill_kernel<<<(n_edges + BLK - 1) / BLK, BLK, 0, stream>>>(
        senders, receivers, off, cursor, elist, n_edges, N);
    // 5. gather into X (also copies node_feat)
    gather_kernel<<<(n2 + 3) / 4, BLK, 0, stream>>>(
        edge_feat, node_feat, off, elist, X, N, totE2);
    // 6. MLP
    mlp_kernel<<<(N + NB - 1) / NB, MBLK, 0, stream>>>(X, W1, b1, W2, b2, out, N);
}

// Round 7
// 596.729 us; speedup vs baseline: 3.0877x; 1.1182x over previous
//
#include <hip/hip_runtime.h>
#include <hip/hip_bf16.h>

// Problem constants
#define D 64
#define IN_DIM 192   // 3*D
#define H 256
#define NB 64        // nodes per MLP block
#define BLK 256
#define SCAN_BLK 512
#define HPAD 280     // Hs row stride in bf16 elems (560B = 140 dw; 140%32=12 -> spread)

typedef __attribute__((ext_vector_type(8))) short bf16x8;
typedef __attribute__((ext_vector_type(4))) float f32x4;

static __device__ __forceinline__ ushort f2b(float x) {
    __hip_bfloat16 hb = __float2bfloat16(x);
    return *reinterpret_cast<ushort*>(&hb);
}

// ---------------------------------------------------------------------------
// Workspace layout (16B-aligned sections):
//   Xb     : N*192 ushort (bf16)   19.2 MB
//   deg    : 2N ints
//   cursor : 2N ints
//   off    : 2N ints
//   bsums  : 256 ints
//   elist  : 2E ints
//   W1T    : 256*192 ushort (bf16, transposed W1)
//   W2T    : 64*256 ushort  (bf16, transposed W2)
// ---------------------------------------------------------------------------

__global__ void zero_kernel(int* __restrict__ p, int n) {
    int i = blockIdx.x * blockDim.x + threadIdx.x;
    for (; i < n; i += gridDim.x * blockDim.x) p[i] = 0;
}

__global__ void hist_kernel(const int* __restrict__ senders,
                            const int* __restrict__ receivers,
                            int* __restrict__ deg, int n_edges, int N) {
    int e = blockIdx.x * blockDim.x + threadIdx.x;
    if (e >= n_edges) return;
    atomicAdd(&deg[receivers[e]], 1);
    atomicAdd(&deg[N + senders[e]], 1);
}

__global__ void scan_a_kernel(const int* __restrict__ deg, int* __restrict__ off,
                              int* __restrict__ bsums, int n) {
    __shared__ int s[SCAN_BLK];
    int t = threadIdx.x;
    int gid = blockIdx.x * SCAN_BLK + t;
    int v = (gid < n) ? deg[gid] : 0;
    s[t] = v;
    for (int ofs = 1; ofs < SCAN_BLK; ofs <<= 1) {
        __syncthreads();
        int x = (t >= ofs) ? s[t - ofs] : 0;
        __syncthreads();
        s[t] += x;
    }
    __syncthreads();
    if (gid < n) off[gid] = s[t] - v;          // exclusive
    if (t == SCAN_BLK - 1) bsums[blockIdx.x] = s[t];
}

__global__ void scan_b_kernel(int* __restrict__ bsums, int nb) {
    __shared__ int s[256];
    int t = threadIdx.x;
    int v = (t < nb) ? bsums[t] : 0;
    s[t] = v;
    for (int ofs = 1; ofs < 256; ofs <<= 1) {
        __syncthreads();
        int x = (t >= ofs) ? s[t - ofs] : 0;
        __syncthreads();
        s[t] += x;
    }
    __syncthreads();
    if (t < nb) bsums[t] = s[t] - v;           // exclusive
}

__global__ void scan_c_kernel(int* __restrict__ off, const int* __restrict__ bsums, int n) {
    int gid = blockIdx.x * SCAN_BLK + threadIdx.x;
    if (gid < n) off[gid] += bsums[blockIdx.x];
}

__global__ void fill_kernel(const int* __restrict__ senders,
                            const int* __restrict__ receivers,
                            const int* __restrict__ off,
                            int* __restrict__ cursor,
                            int* __restrict__ elist, int n_edges, int N) {
    int e = blockIdx.x * blockDim.x + threadIdx.x;
    if (e >= n_edges) return;
    int r = receivers[e];
    int p = atomicAdd(&cursor[r], 1);
    elist[off[r] + p] = e;
    int sd = senders[e];
    int q = atomicAdd(&cursor[N + sd], 1);
    elist[off[N + sd] + q] = e;
}

// Transpose + bf16-convert weights: W1T[h][k] = W1[k][h], W2T[d][h] = W2[h][d]
__global__ void convw_kernel(const float* __restrict__ W1,
                             const float* __restrict__ W2,
                             ushort* __restrict__ W1T,
                             ushort* __restrict__ W2T) {
    int i = blockIdx.x * BLK + threadIdx.x;
    if (i < 49152) {                            // 256*192
        int h = i / IN_DIM, k = i - h * IN_DIM;
        W1T[i] = f2b(W1[(size_t)k * H + h]);
    } else if (i < 49152 + 16384) {             // 64*256
        int j = i - 49152;
        int d = j / H, hh = j - d * H;
        W2T[j] = f2b(W2[(size_t)hh * D + d]);
    }
}

// ---------------------------------------------------------------------------
// Gather: one wave per segment; sub = lane>>4 (edge slot), c4 = lane&15.
// 8 independent edge loads in flight. Writes X in bf16.
// ---------------------------------------------------------------------------
__global__ void gather_kernel(const float* __restrict__ edge_feat,
                              const float* __restrict__ node_feat,
                              const int* __restrict__ off,
                              const int* __restrict__ elist,
                              ushort* __restrict__ Xb, int N, int totE2) {
    int lane = threadIdx.x & 63;
    int seg = blockIdx.x * 4 + (threadIdx.x >> 6);
    if (seg >= 2 * N) return;
    int beg = off[seg];
    int end = (seg + 1 < 2 * N) ? off[seg + 1] : totE2;
    const int sub = lane >> 4;
    const int c4  = lane & 15;

    float4 a0 = make_float4(0.f, 0.f, 0.f, 0.f);
    float4 a1 = make_float4(0.f, 0.f, 0.f, 0.f);
    int i = beg + sub;
    for (; i + 4 < end; i += 8) {
        int e0 = elist[i];
        int e1 = elist[i + 4];
        const float4 v0 = *(const float4*)(edge_feat + (size_t)e0 * D + c4 * 4);
        const float4 v1 = *(const float4*)(edge_feat + (size_t)e1 * D + c4 * 4);
        a0.x += v0.x; a0.y += v0.y; a0.z += v0.z; a0.w += v0.w;
        a1.x += v1.x; a1.y += v1.y; a1.z += v1.z; a1.w += v1.w;
    }
    if (i < end) {
        int e = elist[i];
        const float4 v = *(const float4*)(edge_feat + (size_t)e * D + c4 * 4);
        a0.x += v.x; a0.y += v.y; a0.z += v.z; a0.w += v.w;
    }
    float4 a;
    a.x = a0.x + a1.x; a.y = a0.y + a1.y; a.z = a0.z + a1.z; a.w = a0.w + a1.w;
    a.x += __shfl_xor(a.x, 16); a.y += __shfl_xor(a.y, 16);
    a.z += __shfl_xor(a.z, 16); a.w += __shfl_xor(a.w, 16);
    a.x += __shfl_xor(a.x, 32); a.y += __shfl_xor(a.y, 32);
    a.z += __shfl_xor(a.z, 32); a.w += __shfl_xor(a.w, 32);

    ushort4 ub;
    ub.x = f2b(a.x); ub.y = f2b(a.y); ub.z = f2b(a.z); ub.w = f2b(a.w);

    if (seg < N) {
        ushort* row = Xb + (size_t)seg * IN_DIM;
        if (lane < 16) *(ushort4*)(row + 4 * c4) = ub;
        row[128 + lane] = f2b(node_feat[(size_t)seg * D + lane]);
    } else {
        if (lane < 16)
            *(ushort4*)(Xb + (size_t)(seg - N) * IN_DIM + D + 4 * c4) = ub;
    }
}

// ---------------------------------------------------------------------------
// MFMA MLP: out = relu(X@W1 + b1)@W2 + b2, bf16 inputs, fp32 accumulate.
// Block = 64 nodes, 256 threads (4 waves); wave w owns nodes [w*16, w*16+16).
// Layer 1: A-frags from global bf16 X, B-frags from global W1T. 16 col-tiles
//          x 6 K-steps = 96 MFMAs/wave -> acc[16] (64 VGPR).
// H roundtrip: relu(acc+b1) -> bf16 LDS Hs[64][HPAD] (wave-private rows).
// Layer 2: A-frags from Hs, B-frags from W2T. 4 col-tiles x 8 K-steps.
// MFMA frag layout (gfx950 16x16x32): A: m=lane&15, k=(lane>>4)*8+j;
//                                     D: n=lane&15, m=(lane>>4)*4+reg.
// ---------------------------------------------------------------------------
__global__ __launch_bounds__(BLK, 4) void mlp_mfma_kernel(
    const ushort* __restrict__ Xb,
    const ushort* __restrict__ W1T, const float* __restrict__ b1,
    const ushort* __restrict__ W2T, const float* __restrict__ b2,
    float* __restrict__ out, int N) {
    __shared__ __align__(16) ushort Hs[64 * HPAD];   // 35840 B

    const int t = threadIdx.x;
    const int lane = t & 63;
    const int w = t >> 6;            // wave 0..3
    const int lr = lane & 15;        // A-row / D-col within tile
    const int lk = lane >> 4;        // k-chunk 0..3 / D row-group
    const int nodeBase = blockIdx.x * NB + w * 16;

    // ---- Layer 1 ----
    f32x4 acc[16];
    #pragma unroll
    for (int c = 0; c < 16; ++c) acc[c] = (f32x4){0.f, 0.f, 0.f, 0.f};

    bf16x8 afr[6];
    const ushort* xrow = Xb + (size_t)(nodeBase + lr) * IN_DIM + lk * 8;
    #pragma unroll
    for (int ks = 0; ks < 6; ++ks)
        afr[ks] = *(const bf16x8*)(xrow + ks * 32);

    #pragma unroll
    for (int c = 0; c < 16; ++c) {
        const ushort* wcol = W1T + (size_t)(c * 16 + lr) * IN_DIM + lk * 8;
        #pragma unroll
        for (int ks = 0; ks < 6; ++ks) {
            bf16x8 bfr = *(const bf16x8*)(wcol + ks * 32);
            acc[c] = __builtin_amdgcn_mfma_f32_16x16x32_bf16(afr[ks], bfr, acc[c], 0, 0, 0);
        }
    }

    // ---- bias + relu -> bf16 Hs (wave-private rows) ----
    #pragma unroll
    for (int c = 0; c < 16; ++c) {
        float bv = b1[c * 16 + lr];
        #pragma unroll
        for (int r = 0; r < 4; ++r) {
            float h = fmaxf(acc[c][r] + bv, 0.f);
            int row = w * 16 + lk * 4 + r;
            Hs[row * HPAD + c * 16 + lr] = f2b(h);
        }
    }
    __syncthreads();

    // ---- Layer 2 ----
    bf16x8 a2[8];
    #pragma unroll
    for (int ks = 0; ks < 8; ++ks)
        a2[ks] = *(const bf16x8*)(&Hs[(w * 16 + lr) * HPAD + ks * 32 + lk * 8]);

    f32x4 acc2[4];
    #pragma unroll
    for (int c = 0; c < 4; ++c) acc2[c] = (f32x4){0.f, 0.f, 0.f, 0.f};

    #pragma unroll
    for (int c = 0; c < 4; ++c) {
        const ushort* wcol = W2T + (size_t)(c * 16 + lr) * H + lk * 8;
        #pragma unroll
        for (int ks = 0; ks < 8; ++ks) {
            bf16x8 bfr = *(const bf16x8*)(wcol + ks * 32);
            acc2[c] = __builtin_amdgcn_mfma_f32_16x16x32_bf16(a2[ks], bfr, acc2[c], 0, 0, 0);
        }
    }

    #pragma unroll
    for (int c = 0; c < 4; ++c) {
        float bv = b2[c * 16 + lr];
        #pragma unroll
        for (int r = 0; r < 4; ++r) {
            int node = nodeBase + lk * 4 + r;
            if (node < N)
                out[(size_t)node * D + c * 16 + lr] = acc2[c][r] + bv;
        }
    }
}

// ---------------------------------------------------------------------------
extern "C" void kernel_launch(void* const* d_in, const int* in_sizes, int n_in,
                              void* d_out, int out_size, void* d_ws, size_t ws_size,
                              hipStream_t stream) {
    const float* node_feat = (const float*)d_in[0];
    const float* edge_feat = (const float*)d_in[1];
    const int*   senders   = (const int*)d_in[2];
    const int*   receivers = (const int*)d_in[3];
    const float* W1        = (const float*)d_in[4];
    const float* b1        = (const float*)d_in[5];
    const float* W2        = (const float*)d_in[6];
    const float* b2        = (const float*)d_in[7];
    float* out = (float*)d_out;

    const int N       = in_sizes[0] / D;
    const int n_edges = in_sizes[2];
    const int totE2   = 2 * n_edges;
    const int n2      = 2 * N;

    ushort* Xb   = (ushort*)d_ws;                     // N*192 bf16
    int* deg     = (int*)(Xb + (size_t)N * IN_DIM);   // 2N
    int* cursor  = deg + n2;                          // 2N
    int* off     = cursor + n2;                       // 2N
    int* bsums   = off + n2;                          // 256
    int* elist   = bsums + 256;                       // 2E
    ushort* W1T  = (ushort*)(elist + totE2);          // 256*192
    ushort* W2T  = W1T + 49152;                       // 64*256

    // 1. zero deg + cursor
    zero_kernel<<<196, BLK, 0, stream>>>(deg, 2 * n2);
    // 2. degree histogram
    hist_kernel<<<(n_edges + BLK - 1) / BLK, BLK, 0, stream>>>(
        senders, receivers, deg, n_edges, N);
    // 3. exclusive scan deg -> off
    int nb = (n2 + SCAN_BLK - 1) / SCAN_BLK;          // 196 (<=256 req.)
    scan_a_kernel<<<nb, SCAN_BLK, 0, stream>>>(deg, off, bsums, n2);
    scan_b_kernel<<<1, 256, 0, stream>>>(bsums, nb);
    scan_c_kernel<<<nb, SCAN_BLK, 0, stream>>>(off, bsums, n2);
    // 4. fill edge lists
    fill_kernel<<<(n_edges + BLK - 1) / BLK, BLK, 0, stream>>>(
        senders, receivers, off, cursor, elist, n_edges, N);
    // 5. weight transpose+bf16 (independent; anywhere before mlp)
    convw_kernel<<<(49152 + 16384 + BLK - 1) / BLK, BLK, 0, stream>>>(
        W1, W2, W1T, W2T);
    // 6. gather into bf16 X
    gather_kernel<<<(n2 + 3) / 4, BLK, 0, stream>>>(
        edge_feat, node_feat, off, elist, Xb, N, totE2);
    // 7. MFMA MLP
    mlp_mfma_kernel<<<(N + NB - 1) / NB, BLK, 0, stream>>>(
        Xb, W1T, b1, W2T, b2, out, N);
}